// Round 2
// baseline (78.728 us; speedup 1.0000x reference)
//
#include <hip/hip_runtime.h>
#include <cstdint>

#define D 128
#define NEXP 9

// Pack two fp32 into one uint32 of bf16 (round-to-nearest-even).
__device__ __forceinline__ uint32_t pack2_bf16(float a, float b) {
    uint32_t ua = __builtin_bit_cast(uint32_t, a);
    uint32_t ub = __builtin_bit_cast(uint32_t, b);
    ua += 0x7fffu + ((ua >> 16) & 1u);
    ub += 0x7fffu + ((ub >> 16) & 1u);
    return (ua >> 16) | (ub & 0xffff0000u);
}

// ---------------------------------------------------------------------------
// Kernel A: compact token indices per (clamped) expert into global lists.
// ws layout: int cnt[16] (first 64 B, zeroed by memset node), then
// idx[NEXP][ntok].
// ---------------------------------------------------------------------------
__global__ void ltf_compact(const int* __restrict__ pos, int ntok,
                            int* __restrict__ cnt, int* __restrict__ idx)
{
    __shared__ int lcnt[NEXP];
    __shared__ int gbase[NEXP];
    const int tid = threadIdx.x;
    const int lane = tid & 63;
    const int t = blockIdx.x * 256 + tid;

    if (tid < NEXP) lcnt[tid] = 0;
    __syncthreads();

    int rp = NEXP;  // sentinel: matches no expert
    if (t < ntok) { int p = pos[t]; rp = p < NEXP - 1 ? p : NEXP - 1; }

    unsigned long long m[NEXP];
    #pragma unroll
    for (int r = 0; r < NEXP; ++r) m[r] = __ballot(rp == r);

    int wb = 0;  // this wave's base within the block, held by lane r
    if (lane < NEXP) {
        int cm = __popcll(m[lane]);
        if (cm) wb = atomicAdd(&lcnt[lane], cm);
    }
    __syncthreads();
    if (tid < NEXP) gbase[tid] = lcnt[tid] ? atomicAdd(&cnt[tid], lcnt[tid]) : 0;
    __syncthreads();

    if (t < ntok) {
        int pre = __popcll(m[rp] & ((1ull << lane) - 1ull));
        int slot = gbase[rp] + __shfl(wb, rp) + pre;
        idx[rp * ntok + slot] = t;
    }
}

// ---------------------------------------------------------------------------
// Kernel B: block = (flat 64-token tile, e-half). 256 threads = 4 waves,
// wave handles 16 tokens x 64 e-columns. Lanes 0-31 take tokens 0-7 of the
// wave's 16, lanes 32-63 take tokens 8-15; lane&31 selects an e-pair.
// LDS: 16 KB W half-tile (bf16-packed e-pairs) + 32 KB transposed x = 48 KB
// -> 3 blocks/CU.
// ---------------------------------------------------------------------------
__global__ __launch_bounds__(256) void ltf_apply(
    const float* __restrict__ x, const float* __restrict__ W,
    const float* __restrict__ bias, const int* __restrict__ cnt,
    const int* __restrict__ idx, float* __restrict__ y, int ntok)
{
    __shared__ uint32_t Wp[D * 32];   // 16 KB: Wp[d*32+ep] = bf16(W[r][d][h*64+2ep(+1)])
    __shared__ float XT[4][D * 16];   // 32 KB: per-wave xt[d*16 + tloc]

    const int tid = threadIdx.x;
    const int lane = tid & 63;
    const int wv = tid >> 6;
    const int fid = blockIdx.x >> 1;   // flat tile id
    const int half = blockIdx.x & 1;   // e-half (adjacent blocks share x rows)

    // Map flat tile id -> (expert r, tile) via cnt[] scan (uniform, s_loads).
    int r = -1, tile = 0, acct = 0, cr = 0;
    #pragma unroll
    for (int i = 0; i < NEXP; ++i) {
        int ci = cnt[i];
        int tr = (ci + 63) >> 6;
        if (r < 0 && fid < acct + tr) { r = i; tile = fid - acct; cr = ci; }
        acct += tr;
    }
    if (r < 0) return;  // few dead blocks (worst-case grid sizing)

    const int base = tile * 64;
    int nv = cr - base; if (nv > 64) nv = 64;   // >= 1 guaranteed

    // Stage this expert's e-half of W as bf16 pairs. 4096 pairs / 256 thr.
    const float* Wr = W + (size_t)r * D * D + half * 64;
    #pragma unroll
    for (int i = 0; i < 16; ++i) {
        int id = i * 256 + tid;
        int d = id >> 5, ep = id & 31;
        float2 w = *reinterpret_cast<const float2*>(Wr + d * D + ep * 2);
        Wp[id] = pack2_bf16(w.x, w.y);
    }

    // Stage wave's 16 tokens transposed: xt[d*16 + tloc] = x[tok][d].
    const int* lst = idx + r * ntok + base;
    float* xt = XT[wv];
    #pragma unroll
    for (int p = 0; p < 2; ++p) {
        int tloc = wv * 16 + p * 8 + (lane >> 3);
        int tcl = tloc < nv ? tloc : nv - 1;  // clamp tail to dup (harmless)
        int tok = lst[tcl];
        const int seg = lane & 7;
        const float4* xs = reinterpret_cast<const float4*>(x + (size_t)tok * D + seg * 16);
        #pragma unroll
        for (int j = 0; j < 4; ++j) {
            float4 v = xs[j];
            int d0 = seg * 16 + j * 4;
            int q = p * 8 + (lane >> 3);
            xt[(d0 + 0) * 16 + q] = v.x;
            xt[(d0 + 1) * 16 + q] = v.y;
            xt[(d0 + 2) * 16 + q] = v.z;
            xt[(d0 + 3) * 16 + q] = v.w;
        }
    }
    __syncthreads();

    const int ep = lane & 31;
    const int tsub = lane >> 5;
    const float2 bv = *reinterpret_cast<const float2*>(
        bias + (size_t)r * D + half * 64 + ep * 2);

    int nw = nv - wv * 16; if (nw > 16) nw = 16;
    if (nw > 0) {
        float a0[8], a1[8];
        #pragma unroll
        for (int t = 0; t < 8; ++t) { a0[t] = 0.f; a1[t] = 0.f; }

        // Per d: 1 ds_read_b32 (W pair, 2-way broadcast across half-waves) +
        // 2 broadcast ds_read_b128 (x for 8 tokens) + 2 unpack + 16 FMA.
        #pragma unroll 8
        for (int d = 0; d < D; ++d) {
            uint32_t w2 = Wp[d * 32 + ep];
            float w0 = __builtin_bit_cast(float, w2 << 16);
            float w1 = __builtin_bit_cast(float, w2 & 0xffff0000u);
            const float4* xr = reinterpret_cast<const float4*>(&xt[d * 16 + tsub * 8]);
            float4 va = xr[0];
            float4 vb = xr[1];
            a0[0] += w0 * va.x; a1[0] += w1 * va.x;
            a0[1] += w0 * va.y; a1[1] += w1 * va.y;
            a0[2] += w0 * va.z; a1[2] += w1 * va.z;
            a0[3] += w0 * va.w; a1[3] += w1 * va.w;
            a0[4] += w0 * vb.x; a1[4] += w1 * vb.x;
            a0[5] += w0 * vb.y; a1[5] += w1 * vb.y;
            a0[6] += w0 * vb.z; a1[6] += w1 * vb.z;
            a0[7] += w0 * vb.w; a1[7] += w1 * vb.w;
        }

        #pragma unroll
        for (int t = 0; t < 8; ++t) {
            int tloc = wv * 16 + tsub * 8 + t;
            if (tloc < nv) {
                int tok = lst[tloc];
                float2 o;
                o.x = a0[t] + bv.x;
                o.y = a1[t] + bv.y;
                reinterpret_cast<float2*>(y + (size_t)tok * D + half * 64)[ep] = o;
            }
        }
    }
}

extern "C" void kernel_launch(void* const* d_in, const int* in_sizes, int n_in,
                              void* d_out, int out_size, void* d_ws, size_t ws_size,
                              hipStream_t stream) {
    const int* pos  = (const int*)d_in[0];
    const float* x  = (const float*)d_in[1];
    const float* W  = (const float*)d_in[2];
    const float* b  = (const float*)d_in[3];
    float* y = (float*)d_out;

    const int ntok = in_sizes[0];          // T*B = 8192
    int* cnt = (int*)d_ws;
    int* idx = cnt + 16;

    hipMemsetAsync(d_ws, 0, 64, stream);   // zero cnt (graph-legal memset node)
    ltf_compact<<<(ntok + 255) / 256, 256, 0, stream>>>(pos, ntok, cnt, idx);

    // Worst-case flat tiles: sum ceil(cnt[r]/64) <= ntok/64 + NEXP; x2 e-halves.
    int nblk = 2 * ((ntok + 63) / 64 + NEXP);
    ltf_apply<<<nblk, 256, 0, stream>>>(x, W, b, cnt, idx, y, ntok);
}

// Round 3
// 76.716 us; speedup vs baseline: 1.0262x; 1.0262x over previous
//
#include <hip/hip_runtime.h>
#include <cstdint>

#define D 128
#define NEXP 9
#define TPB 256
#define CH0 512   // chunk size, experts 0..7
#define CH8 128   // chunk size, overflow expert 8 (catches ~4/12 of tokens)

// Pack two fp32 into one uint32 of bf16 (round-to-nearest-even).
__device__ __forceinline__ uint32_t pack2_bf16(float a, float b) {
    uint32_t ua = __builtin_bit_cast(uint32_t, a);
    uint32_t ub = __builtin_bit_cast(uint32_t, b);
    ua += 0x7fffu + ((ua >> 16) & 1u);
    ub += 0x7fffu + ((ub >> 16) & 1u);
    return (ua >> 16) | (ub & 0xffff0000u);
}

// One node, self-compacting blocks. Block = (expert r, token chunk).
// Experts 0-7: chunks of 512 (expect ~43 matched); expert 8: chunks of 128
// (expect ~43 matched) -> ~192 balanced blocks, 1/CU, staged W amortized
// over ~43 tokens. 4 waves; wave processes groups of 8 tokens x 128 e.
__global__ __launch_bounds__(TPB) void ltf_kernel(
    const int* __restrict__ pos, const float* __restrict__ x,
    const float* __restrict__ W, const float* __restrict__ bias,
    float* __restrict__ y, int ntok, int c0)
{
    __shared__ uint32_t Wp[D * (D / 2)];  // 32 KB: W[r] bf16-packed e-pairs, [d][e/2]
    __shared__ float XT[4][D * 8];        // 16 KB: per-wave transposed x, 8 tokens
    __shared__ int lst[CH0];              // 2 KB
    __shared__ int cnt;

    const int tid = threadIdx.x;
    const int lane = tid & 63;
    const int wv = tid >> 6;
    const int bid = blockIdx.x;

    int r, start, C;
    if (bid < 8 * c0) { r = bid / c0; start = (bid - r * c0) * CH0; C = CH0; }
    else              { r = 8; start = (bid - 8 * c0) * CH8; C = CH8; }

    if (tid == 0) cnt = 0;
    __syncthreads();  // cnt=0 visible before LDS atomics

    // --- Self-compact: scan chunk, collect tokens with clamped expert == r.
    const int end = (start + C < ntok) ? start + C : ntok;
    #pragma unroll
    for (int it = 0; it < CH0 / TPB; ++it) {
        int t = start + it * TPB + tid;
        bool m = false;
        if (t < end) {
            int p = pos[t];
            int rp = p < (NEXP - 1) ? p : (NEXP - 1);
            m = (rp == r);
        }
        unsigned long long mask = __ballot(m);
        int nm = __popcll(mask);
        int base = 0;
        if (lane == 0 && nm > 0) base = atomicAdd(&cnt, nm);
        base = __shfl(base, 0);
        if (m) {
            int pre = __popcll(mask & ((1ull << lane) - 1ull));
            lst[base + pre] = t;
        }
    }

    // --- Stage W[r] -> LDS as bf16 pairs (float4 loads: 16/thread).
    const float4* Wr4 = reinterpret_cast<const float4*>(W + (size_t)r * D * D);
    #pragma unroll
    for (int i = 0; i < (D * D / 4) / TPB; ++i) {
        int idx = i * TPB + tid;
        float4 w = Wr4[idx];
        Wp[idx * 2 + 0] = pack2_bf16(w.x, w.y);
        Wp[idx * 2 + 1] = pack2_bf16(w.z, w.w);
    }
    __syncthreads();

    const int nc = cnt;
    float* xt = XT[wv];
    const float2 bv = reinterpret_cast<const float2*>(bias + (size_t)r * D)[lane];

    for (int g = wv; g * 8 < nc; g += 4) {
        const int gb = g * 8;
        int valid = nc - gb; if (valid > 8) valid = 8;

        // Stage 8 token x-vectors transposed: xt[d*8 + t] = x[tok_t][d].
        const int ti = lane >> 3, seg = lane & 7;
        int tsel = ti < valid ? ti : valid - 1;  // clamp tail to dup (harmless)
        int mytok = lst[gb + tsel];
        const float4* xs = reinterpret_cast<const float4*>(x + (size_t)mytok * D + seg * 16);
        #pragma unroll
        for (int j = 0; j < 4; ++j) {
            float4 v = xs[j];
            int d0 = seg * 16 + j * 4;
            xt[(d0 + 0) * 8 + ti] = v.x;
            xt[(d0 + 1) * 8 + ti] = v.y;
            xt[(d0 + 2) * 8 + ti] = v.z;
            xt[(d0 + 3) * 8 + ti] = v.w;
        }

        float a0[8], a1[8];
        #pragma unroll
        for (int t = 0; t < 8; ++t) { a0[t] = 0.f; a1[t] = 0.f; }

        // Per d: 1 ds_read_b32 (W pair, conflict-free) + 2 broadcast
        // ds_read_b128 (x of 8 tokens) + 2 unpack + 16 FMA (~84% density).
        #pragma unroll 4
        for (int d = 0; d < D; ++d) {
            uint32_t w2 = Wp[d * 64 + lane];
            float w0 = __builtin_bit_cast(float, w2 << 16);
            float w1 = __builtin_bit_cast(float, w2 & 0xffff0000u);
            const float4* xr = reinterpret_cast<const float4*>(&xt[d * 8]);
            float4 va = xr[0];
            float4 vb = xr[1];
            a0[0] += w0 * va.x; a1[0] += w1 * va.x;
            a0[1] += w0 * va.y; a1[1] += w1 * va.y;
            a0[2] += w0 * va.z; a1[2] += w1 * va.z;
            a0[3] += w0 * va.w; a1[3] += w1 * va.w;
            a0[4] += w0 * vb.x; a1[4] += w1 * vb.x;
            a0[5] += w0 * vb.y; a1[5] += w1 * vb.y;
            a0[6] += w0 * vb.z; a1[6] += w1 * vb.z;
            a0[7] += w0 * vb.w; a1[7] += w1 * vb.w;
        }

        #pragma unroll
        for (int t = 0; t < 8; ++t) {
            if (t < valid) {
                int tk = lst[gb + t];
                float2 o;
                o.x = a0[t] + bv.x;
                o.y = a1[t] + bv.y;
                reinterpret_cast<float2*>(y + (size_t)tk * D)[lane] = o;
            }
        }
    }
}

extern "C" void kernel_launch(void* const* d_in, const int* in_sizes, int n_in,
                              void* d_out, int out_size, void* d_ws, size_t ws_size,
                              hipStream_t stream) {
    const int* pos  = (const int*)d_in[0];
    const float* x  = (const float*)d_in[1];
    const float* W  = (const float*)d_in[2];
    const float* b  = (const float*)d_in[3];
    float* y = (float*)d_out;

    const int ntok = in_sizes[0];            // T*B = 8192
    const int c0 = (ntok + CH0 - 1) / CH0;   // chunks per expert 0..7
    const int c8 = (ntok + CH8 - 1) / CH8;   // fine chunks for expert 8
    ltf_kernel<<<8 * c0 + c8, TPB, 0, stream>>>(pos, x, W, b, y, ntok, c0);
}

// Round 4
// 66.456 us; speedup vs baseline: 1.1847x; 1.1544x over previous
//
#include <hip/hip_runtime.h>
#include <cstdint>

#define D 128
#define NEXP 9
#define TPB 256
#define CH0 512   // chunk size, experts 0..7 (expect ~43 matched)
#define CH8 128   // chunk size, overflow expert 8 (catches pos 8..11 = 4/12)

typedef __bf16 bf16x8_t __attribute__((ext_vector_type(8)));
typedef float  f32x4_t  __attribute__((ext_vector_type(4)));

union FragA { uint32_t u[4]; bf16x8_t v; };

// Pack two fp32 into one uint32 of bf16 (round-to-nearest-even).
__device__ __forceinline__ uint32_t pack2_bf16(float a, float b) {
    uint32_t ua = __builtin_bit_cast(uint32_t, a);
    uint32_t ub = __builtin_bit_cast(uint32_t, b);
    ua += 0x7fffu + ((ua >> 16) & 1u);
    ub += 0x7fffu + ((ub >> 16) & 1u);
    return (ua >> 16) | (ub & 0xffff0000u);
}

// One node. Block = (expert r, token chunk); self-compacts its chunk, stages
// W[r] in MFMA B-fragment order (bf16), then waves run 16-token x 128-e
// tiles on the matrix pipe: mfma_f32_16x16x32_bf16, M=tokens, N=e, K=d.
//
// Fragment layouts (gfx950, 16x16x32):
//   A: lane holds A[m=lane&15][k=(lane>>4)*8+j], j=0..7   (m120-verified)
//   B: lane holds B[k=(lane>>4)*8+j][n=lane&15]           (symmetric mapping)
//   D: lane,reg -> row m=(lane>>4)*4+reg, col n=lane&15   (m89-verified)
__global__ __launch_bounds__(TPB) void ltf_kernel(
    const int* __restrict__ pos, const float* __restrict__ x,
    const float* __restrict__ W, const float* __restrict__ bias,
    float* __restrict__ y, int ntok, int c0)
{
    // Wf: 32 tiles (kt=0..3, n=0..7) x 64 lanes x 16 B = 32 KB, frag-order.
    __shared__ uint32_t Wf[8192];
    __shared__ int lst[CH0];   // capacity == chunk size: cannot overflow
    __shared__ int cnt;

    const int tid  = threadIdx.x;
    const int lane = tid & 63;
    const int wv   = tid >> 6;
    const int bid  = blockIdx.x;

    int r, start, C;
    if (bid < 8 * c0) { r = bid / c0; start = (bid - r * c0) * CH0; C = CH0; }
    else              { r = 8; start = (bid - 8 * c0) * CH8; C = CH8; }

    if (tid == 0) cnt = 0;
    __syncthreads();

    // --- Self-compact: tokens in chunk with clamped expert == r.
    const int end = (start + C < ntok) ? start + C : ntok;
    #pragma unroll
    for (int it = 0; it < CH0 / TPB; ++it) {
        int t = start + it * TPB + tid;
        bool m = false;
        if (t < end) {
            int p = pos[t];
            int rp = p < (NEXP - 1) ? p : (NEXP - 1);
            m = (rp == r);
        }
        unsigned long long mask = __ballot(m);
        int nm = __popcll(mask);
        int base = 0;
        if (lane == 0 && nm > 0) base = atomicAdd(&cnt, nm);
        base = __shfl(base, 0);
        if (m) {
            int pre = __popcll(mask & ((1ull << lane) - 1ull));
            lst[base + pre] = t;
        }
    }

    // --- Stage W[r] -> LDS in B-frag order, bf16. 2048 slots / 256 threads.
    // Slot s = tile T * 64 + lane l; tile T = (kt<<3)|n; lane l = (q<<4)|m.
    // Frag element j = bf16( W[r][kt*32 + q*8 + j][n*16 + m] ).
    const float* Wr = W + (size_t)r * D * D;
    #pragma unroll
    for (int i = 0; i < 8; ++i) {
        int s = i * TPB + tid;
        int l = s & 63, T = s >> 6;
        int q = l >> 4, m = l & 15;
        int kt = T >> 3, n = T & 7;
        const float* src = Wr + (kt * 32 + q * 8) * D + n * 16 + m;
        uint32_t u0 = pack2_bf16(src[0 * D], src[1 * D]);
        uint32_t u1 = pack2_bf16(src[2 * D], src[3 * D]);
        uint32_t u2 = pack2_bf16(src[4 * D], src[5 * D]);
        uint32_t u3 = pack2_bf16(src[6 * D], src[7 * D]);
        *reinterpret_cast<uint4*>(&Wf[s * 4]) = uint4{u0, u1, u2, u3};
    }
    __syncthreads();

    const int nc = cnt;
    const int q = lane >> 4, mloc = lane & 15;

    // Per-lane bias for its 8 e-columns (n*16 + mloc).
    float bvn[8];
    #pragma unroll
    for (int n = 0; n < 8; ++n) bvn[n] = bias[(size_t)r * D + n * 16 + mloc];

    const int rounds = (nc + 63) >> 6;
    for (int rd = 0; rd < rounds; ++rd) {
        const int b16 = rd * 64 + wv * 16;   // this wave's 16-token group
        if (b16 >= nc) continue;

        int ta = b16 + mloc; if (ta >= nc) ta = nc - 1;  // dup tail (harmless)
        const int tokA = lst[ta];
        const float4* xrow = reinterpret_cast<const float4*>(x + (size_t)tokA * D);

        f32x4_t acc[8];
        #pragma unroll
        for (int n = 0; n < 8; ++n) acc[n] = f32x4_t{0.f, 0.f, 0.f, 0.f};

        #pragma unroll
        for (int kt = 0; kt < 4; ++kt) {
            // A-frag: x[tokA][kt*32 + q*8 .. +7] -> bf16x8, built in regs.
            float4 va = xrow[kt * 8 + q * 2];
            float4 vb = xrow[kt * 8 + q * 2 + 1];
            FragA a;
            a.u[0] = pack2_bf16(va.x, va.y);
            a.u[1] = pack2_bf16(va.z, va.w);
            a.u[2] = pack2_bf16(vb.x, vb.y);
            a.u[3] = pack2_bf16(vb.z, vb.w);
            #pragma unroll
            for (int n = 0; n < 8; ++n) {
                bf16x8_t bf = *reinterpret_cast<const bf16x8_t*>(
                    &Wf[(kt * 8 + n) * 256 + lane * 4]);
                acc[n] = __builtin_amdgcn_mfma_f32_16x16x32_bf16(
                    a.v, bf, acc[n], 0, 0, 0);
            }
        }

        // Epilogue: lane (q,reg) holds token row m = q*4+reg, col n*16+mloc.
        #pragma unroll
        for (int reg = 0; reg < 4; ++reg) {
            int tloc = b16 + q * 4 + reg;
            if (tloc < nc) {
                int tok = lst[tloc];
                float* yr = y + (size_t)tok * D + mloc;
                #pragma unroll
                for (int n = 0; n < 8; ++n)
                    yr[n * 16] = acc[n][reg] + bvn[n];
            }
        }
    }
}

extern "C" void kernel_launch(void* const* d_in, const int* in_sizes, int n_in,
                              void* d_out, int out_size, void* d_ws, size_t ws_size,
                              hipStream_t stream) {
    const int* pos  = (const int*)d_in[0];
    const float* x  = (const float*)d_in[1];
    const float* W  = (const float*)d_in[2];
    const float* b  = (const float*)d_in[3];
    float* y = (float*)d_out;

    const int ntok = in_sizes[0];            // T*B = 8192
    const int c0 = (ntok + CH0 - 1) / CH0;   // chunks per expert 0..7
    const int c8 = (ntok + CH8 - 1) / CH8;   // fine chunks for expert 8
    ltf_kernel<<<8 * c0 + c8, TPB, 0, stream>>>(pos, x, W, b, y, ntok, c0);
}